// Round 2
// baseline (741.720 us; speedup 1.0000x reference)
//
#include <hip/hip_runtime.h>
#include <cstddef>

#define BB 2048
#define TT 200
#define HH 256
#define KK 8

// workspace layout (in floats)
#define WS_M2T  0        // 257 rows x 256 (row 256 = dvec = Wk@bq)
#define WS_EVEC 65792    // 256  (Wq@bk)
#define WS_F    66048    // 1    (bk.bq)
#define WS_QK   66304    // 2048*256 pre-scaled qk vectors

__device__ __forceinline__ float wred_sum(float v) {
#pragma unroll
  for (int off = 32; off; off >>= 1) v += __shfl_xor(v, off);
  return v;
}
__device__ __forceinline__ float wred_max(float v) {
#pragma unroll
  for (int off = 32; off; off >>= 1) v = fmaxf(v, __shfl_xor(v, off));
  return v;
}

// ---------------------------------------------------------------------------
// prep_gemm: M2T[l][i] = sum_j Wq[l][j]*Wk[i][j].  64x64 tiles, both operands
// staged coalesced in LDS (K-major rows), grid 16.
// ---------------------------------------------------------------------------
__global__ __launch_bounds__(256) void prep_gemm(
    const float* __restrict__ Wq, const float* __restrict__ Wk,
    float* __restrict__ M2T) {
  const int tid = threadIdx.x;
  const int l0 = (blockIdx.x >> 2) * 64, i0 = (blockIdx.x & 3) * 64;
  __shared__ float As[64][68], Bs[64][68];
  const int tl = tid >> 4, ti = tid & 15;
  float acc[4][4];
#pragma unroll
  for (int r = 0; r < 4; ++r)
#pragma unroll
    for (int c = 0; c < 4; ++c) acc[r][c] = 0.f;

  for (int kc = 0; kc < 4; ++kc) {
    const int k0 = kc * 64;
#pragma unroll
    for (int it = 0; it < 4; ++it) {
      int idx = it * 256 + tid;
      int row = idx >> 4, c4 = idx & 15;
      *(float4*)(&As[row][c4 * 4]) =
          *(const float4*)(Wq + (size_t)(l0 + row) * HH + k0 + c4 * 4);
      *(float4*)(&Bs[row][c4 * 4]) =
          *(const float4*)(Wk + (size_t)(i0 + row) * HH + k0 + c4 * 4);
    }
    __syncthreads();
#pragma unroll 4
    for (int k4 = 0; k4 < 16; ++k4) {
      float4 a4[4], b4[4];
#pragma unroll
      for (int r = 0; r < 4; ++r) a4[r] = *(const float4*)(&As[tl * 4 + r][k4 * 4]);
#pragma unroll
      for (int c = 0; c < 4; ++c) b4[c] = *(const float4*)(&Bs[ti * 4 + c][k4 * 4]);
#pragma unroll
      for (int r = 0; r < 4; ++r)
#pragma unroll
        for (int c = 0; c < 4; ++c)
          acc[r][c] += a4[r].x * b4[c].x + a4[r].y * b4[c].y +
                       a4[r].z * b4[c].z + a4[r].w * b4[c].w;
    }
    __syncthreads();
  }
#pragma unroll
  for (int r = 0; r < 4; ++r) {
    float4 o = make_float4(acc[r][0], acc[r][1], acc[r][2], acc[r][3]);
    *(float4*)(M2T + (size_t)(l0 + tl * 4 + r) * HH + i0 + ti * 4) = o;
  }
}

// ---------------------------------------------------------------------------
// bias_kernel: grid 513.  blocks 0..255: dvec[i]=Wk[i].bq -> M2T row 256;
// 256..511: evec[l]=Wq[l].bk; 512: f = bk.bq.  Coalesced row dot + reduce.
// ---------------------------------------------------------------------------
__global__ __launch_bounds__(256) void bias_kernel(
    const float* __restrict__ Wq, const float* __restrict__ bq,
    const float* __restrict__ Wk, const float* __restrict__ bk,
    float* __restrict__ M2T, float* __restrict__ evec, float* __restrict__ fsc) {
  const int id = blockIdx.x, tid = threadIdx.x;
  __shared__ float s4[4];
  const float* row;
  const float* vec;
  float* outp;
  if (id < 256)      { row = Wk + (size_t)id * HH;        vec = bq; outp = M2T + (size_t)256 * HH + id; }
  else if (id < 512) { row = Wq + (size_t)(id - 256) * HH; vec = bk; outp = evec + (id - 256); }
  else               { row = bk;                           vec = bq; outp = fsc; }
  float p = row[tid] * vec[tid];
  p = wred_sum(p);
  if ((tid & 63) == 0) s4[tid >> 6] = p;
  __syncthreads();
  if (tid == 0) *outp = s4[0] + s4[1] + s4[2] + s4[3];
}

// ---------------------------------------------------------------------------
// qkg: QK[b][i] = ( sum_{l<256} cs[b][l]*M2T[l][i] + dvec[i] ) / 16
// via augmented row 256 (coeff 1).  Grid 256, 8 b per block.
// ---------------------------------------------------------------------------
__global__ __launch_bounds__(256, 4) void qkg_kernel(
    const float* __restrict__ CS, const float* __restrict__ M2T,
    float* __restrict__ QK) {
  const int tid = threadIdx.x, bb = blockIdx.x;
  __shared__ float s_cs[8][260];
#pragma unroll
  for (int it = 0; it < 2; ++it) {
    int idx = it * 256 + tid;
    int row = idx >> 6, c4 = idx & 63;
    *(float4*)(&s_cs[row][c4 * 4]) =
        *(const float4*)(CS + (size_t)(bb * 8 + row) * HH + c4 * 4);
  }
  if (tid < 8) s_cs[tid][256] = 1.0f;
  __syncthreads();
  const int bloc = tid >> 5, tx = tid & 31;
  float acc[8];
#pragma unroll
  for (int c = 0; c < 8; ++c) acc[c] = 0.f;
#pragma unroll 4
  for (int l = 0; l < 257; ++l) {
    float a = s_cs[bloc][l];
    const float* mr = M2T + (size_t)l * HH + tx * 8;
    float4 m0 = *(const float4*)(mr);
    float4 m1 = *(const float4*)(mr + 4);
    acc[0] += a * m0.x; acc[1] += a * m0.y; acc[2] += a * m0.z; acc[3] += a * m0.w;
    acc[4] += a * m1.x; acc[5] += a * m1.y; acc[6] += a * m1.z; acc[7] += a * m1.w;
  }
  float* op = QK + (size_t)(bb * 8 + bloc) * HH + tx * 8;
  *(float4*)(op)     = make_float4(acc[0] * 0.0625f, acc[1] * 0.0625f,
                                   acc[2] * 0.0625f, acc[3] * 0.0625f);
  *(float4*)(op + 4) = make_float4(acc[4] * 0.0625f, acc[5] * 0.0625f,
                                   acc[6] * 0.0625f, acc[7] * 0.0625f);
}

// ---------------------------------------------------------------------------
// attn: one block per b.  scores -> softmax -> top-8 -> fused summary GEMM.
// ---------------------------------------------------------------------------
__global__ __launch_bounds__(256, 4) void attn_kernel(
    const float* __restrict__ CS, const float* __restrict__ X,
    const int* __restrict__ VM,
    const float* __restrict__ QK, const float* __restrict__ evec,
    const float* __restrict__ fsc,
    const float* __restrict__ Wv, const float* __restrict__ bvv,
    float* __restrict__ out) {
  const int tid = threadIdx.x, b = blockIdx.x;
  const int w = tid >> 6, lane = tid & 63;
  __shared__ float s_qk[HH];
  __shared__ float s_sc[TT], s_cand[TT];
  __shared__ int   s_hist[TT];
  __shared__ float s_c4[4], s_r4[4], s_m4[4];
  __shared__ int   s_selI[KK];
  __shared__ float s_selV[KK];
  __shared__ float s_dS;
  __shared__ float xs[8][264];
  __shared__ float red[4][260];

  // ---- mask + per-wave count; qk row; qb partial ----
  int m = (tid < TT) ? (VM[(size_t)b * TT + tid] != 0) : 0;
  unsigned long long bal = __ballot(m);
  if (lane == 0) s_c4[w] = (float)__popcll(bal);
  s_qk[tid] = QK[(size_t)b * HH + tid];                 // pre-scaled by 1/16
  float rq = CS[(size_t)b * HH + tid] * evec[tid];
  rq = wred_sum(rq);
  if (lane == 0) s_r4[w] = rq;
  __syncthreads();

  const int cnt = (int)(s_c4[0] + s_c4[1] + s_c4[2] + s_c4[3]);
  if (tid < TT) s_hist[tid] = (m && (tid < cnt - 1)) ? 1 : 0;
  const float qb = (s_r4[0] + s_r4[1] + s_r4[2] + s_r4[3] + fsc[0]) * 0.0625f;

  // ---- scores: wave w owns t in [w*50, w*50+50); 4-row batches ----
  {
    const float* xrow = X + (size_t)b * TT * HH;
    const float4 q4 = ((const float4*)s_qk)[lane];
    const int tb = w * 50;
    for (int i = 0; i < 48; i += 4) {
      const float* p0 = xrow + (size_t)(tb + i) * HH + lane * 4;
      float4 xa = *(const float4*)(p0);
      float4 xb = *(const float4*)(p0 + HH);
      float4 xc = *(const float4*)(p0 + 2 * HH);
      float4 xd = *(const float4*)(p0 + 3 * HH);
      float pa = xa.x * q4.x + xa.y * q4.y + xa.z * q4.z + xa.w * q4.w;
      float pb = xb.x * q4.x + xb.y * q4.y + xb.z * q4.z + xb.w * q4.w;
      float pc = xc.x * q4.x + xc.y * q4.y + xc.z * q4.z + xc.w * q4.w;
      float pd = xd.x * q4.x + xd.y * q4.y + xd.z * q4.z + xd.w * q4.w;
#pragma unroll
      for (int off = 32; off; off >>= 1) {
        pa += __shfl_xor(pa, off);
        pb += __shfl_xor(pb, off);
        pc += __shfl_xor(pc, off);
        pd += __shfl_xor(pd, off);
      }
      if (lane == 0) {
        s_sc[tb + i]     = pa + qb;
        s_sc[tb + i + 1] = pb + qb;
        s_sc[tb + i + 2] = pc + qb;
        s_sc[tb + i + 3] = pd + qb;
      }
    }
#pragma unroll
    for (int t = tb + 48; t < tb + 50; ++t) {
      float4 xv = *(const float4*)(xrow + (size_t)t * HH + lane * 4);
      float p = xv.x * q4.x + xv.y * q4.y + xv.z * q4.z + xv.w * q4.w;
      p = wred_sum(p);
      if (lane == 0) s_sc[t] = p + qb;
    }
  }
  __syncthreads();

  // ---- masked softmax: wave reduce + 4-entry combine ----
  const int hist = (tid < TT) ? s_hist[tid] : 0;
  float v = hist ? s_sc[tid] : -3.4e38f;
  float wm = wred_max(v);
  if (lane == 0) s_m4[w] = wm;
  __syncthreads();
  const float mx = fmaxf(fmaxf(s_m4[0], s_m4[1]), fmaxf(s_m4[2], s_m4[3]));
  float p = hist ? expf(v - mx) : 0.f;
  float ws_ = wred_sum(p);
  if (lane == 0) s_r4[w] = ws_;
  __syncthreads();
  const float denom = s_r4[0] + s_r4[1] + s_r4[2] + s_r4[3];
  if (tid < TT) s_cand[tid] = hist ? (p / denom) : -1.0f;
  __syncthreads();

  // ---- top-8 (wave 0): value desc, index asc -- matches lax.top_k ----
  if (tid < 64) {
    float lv[4]; int lt[4];
#pragma unroll
    for (int q = 0; q < 4; ++q) {
      int t = tid + 64 * q;
      lv[q] = (t < TT) ? s_cand[t] : -2.0f;
      lt[q] = t;
    }
    for (int r = 0; r < KK; ++r) {
      float bv = -2.5f; int bi = 1 << 30;
#pragma unroll
      for (int q = 0; q < 4; ++q)
        if (lv[q] > bv) { bv = lv[q]; bi = lt[q]; }
#pragma unroll
      for (int off = 32; off; off >>= 1) {
        float ov = __shfl_xor(bv, off);
        int   oi = __shfl_xor(bi, off);
        if (ov > bv || (ov == bv && oi < bi)) { bv = ov; bi = oi; }
      }
      if (tid == 0) { s_selI[r] = bi; s_selV[r] = bv; }
#pragma unroll
      for (int q = 0; q < 4; ++q)
        if (lt[q] == bi) lv[q] = -3.0f;
    }
    if (tid == 0) {
      float S = 0.f;
#pragma unroll
      for (int r = 0; r < KK; ++r) S += fmaxf(s_selV[r], 0.f);
      s_dS = fmaxf(S, 1.1920929e-07f);
    }
  }
  __syncthreads();

  // ---- fused summary: group ty owns selected slot ty; 8 cols per thread ----
  const int ty = tid >> 5, tx = tid & 31;
  {
    const int tsel = s_selI[ty];
    const float* xr = X + ((size_t)b * TT + tsel) * HH + tx * 8;
    *(float4*)(&xs[ty][tx * 8])     = *(const float4*)(xr);
    *(float4*)(&xs[ty][tx * 8 + 4]) = *(const float4*)(xr + 4);
  }
  __syncthreads();
  float acc[8];
#pragma unroll
  for (int c = 0; c < 8; ++c) acc[c] = 0.f;
  {
    const float* wvp = Wv + tx * 8;
#pragma unroll 2
    for (int k4 = 0; k4 < 64; ++k4) {
      float4 a4 = *(const float4*)(&xs[ty][k4 * 4]);
#pragma unroll
      for (int kk = 0; kk < 4; ++kk) {
        const float* wrow = wvp + (size_t)(k4 * 4 + kk) * HH;
        float4 w0 = *(const float4*)(wrow);
        float4 w1 = *(const float4*)(wrow + 4);
        float av = (kk == 0) ? a4.x : (kk == 1) ? a4.y : (kk == 2) ? a4.z : a4.w;
        acc[0] += av * w0.x; acc[1] += av * w0.y; acc[2] += av * w0.z; acc[3] += av * w0.w;
        acc[4] += av * w1.x; acc[5] += av * w1.y; acc[6] += av * w1.z; acc[7] += av * w1.w;
      }
    }
  }
  {
    const float wr = fmaxf(s_selV[ty], 0.f) / s_dS;
    float4 b0 = *(const float4*)(bvv + tx * 8);
    float4 b1 = *(const float4*)(bvv + tx * 8 + 4);
    float val[8];
    val[0] = wr * fmaxf(acc[0] + b0.x, 0.f); val[1] = wr * fmaxf(acc[1] + b0.y, 0.f);
    val[2] = wr * fmaxf(acc[2] + b0.z, 0.f); val[3] = wr * fmaxf(acc[3] + b0.w, 0.f);
    val[4] = wr * fmaxf(acc[4] + b1.x, 0.f); val[5] = wr * fmaxf(acc[5] + b1.y, 0.f);
    val[6] = wr * fmaxf(acc[6] + b1.z, 0.f); val[7] = wr * fmaxf(acc[7] + b1.w, 0.f);
#pragma unroll
    for (int c = 0; c < 8; ++c) val[c] += __shfl_xor(val[c], 32);
    if ((tid & 32) == 0) {
      *(float4*)(&red[w][tx * 8])     = make_float4(val[0], val[1], val[2], val[3]);
      *(float4*)(&red[w][tx * 8 + 4]) = make_float4(val[4], val[5], val[6], val[7]);
    }
  }
  __syncthreads();
  out[(size_t)b * HH + tid] =
      red[0][tid] + red[1][tid] + red[2][tid] + red[3][tid];

  // ---- attn row + selected ----
  float* out_attn = out + (size_t)BB * HH + (size_t)b * TT;
  if (tid < TT) out_attn[tid] = 0.f;
  __syncthreads();
  if (tid < KK) {
    float vvv = s_selV[tid];
    int   bi  = s_selI[tid];
    float wf  = fmaxf(vvv, 0.f) / s_dS;
    int ok = (vvv >= 0.f);
    if (ok) out_attn[bi] = wf;
    out[(size_t)BB * HH + (size_t)BB * TT + (size_t)b * KK + tid] =
        ok ? (float)bi : -1.0f;
  }
}

// ---------------------------------------------------------------------------
extern "C" void kernel_launch(void* const* d_in, const int* in_sizes, int n_in,
                              void* d_out, int out_size, void* d_ws, size_t ws_size,
                              hipStream_t stream) {
  const float* cs  = (const float*)d_in[0];
  const float* X   = (const float*)d_in[1];
  const int*   vm  = (const int*)d_in[2];
  const float* Wq  = (const float*)d_in[3];
  const float* bq  = (const float*)d_in[4];
  const float* Wk  = (const float*)d_in[5];
  const float* bk  = (const float*)d_in[6];
  const float* Wv  = (const float*)d_in[7];
  const float* bvp = (const float*)d_in[8];
  float* out = (float*)d_out;
  float* ws  = (float*)d_ws;

  float* M2T  = ws + WS_M2T;
  float* evec = ws + WS_EVEC;
  float* fsc  = ws + WS_F;
  float* QK   = ws + WS_QK;

  hipLaunchKernelGGL(prep_gemm, dim3(16), dim3(256), 0, stream, Wq, Wk, M2T);
  hipLaunchKernelGGL(bias_kernel, dim3(513), dim3(256), 0, stream,
                     Wq, bq, Wk, bk, M2T, evec, fsc);
  hipLaunchKernelGGL(qkg_kernel, dim3(BB / 8), dim3(256), 0, stream,
                     cs, M2T, QK);
  hipLaunchKernelGGL(attn_kernel, dim3(BB), dim3(256), 0, stream,
                     cs, X, vm, QK, evec, fsc, Wv, bvp, out);
}

// Round 3
// 639.749 us; speedup vs baseline: 1.1594x; 1.1594x over previous
//
#include <hip/hip_runtime.h>
#include <cstddef>

#define BB 2048
#define TT 200
#define HH 256
#define KK 8
#define XP 260   // LDS pitch for gathered rows in summ

// workspace layout (in floats)
#define WS_M2T  0        // 257 rows x 256 (row 256 = dvec = Wk@bq)
#define WS_EVEC 65792    // 256  (Wq@bk)
#define WS_F    66048    // 1    (bk.bq)
#define WS_QK   66304    // 2048*256 pre-scaled qk vectors
#define WS_IDX  590592   // 16384 ints
#define WS_W    606976   // 16384 floats

__device__ __forceinline__ float wred_sum(float v) {
#pragma unroll
  for (int off = 32; off; off >>= 1) v += __shfl_xor(v, off);
  return v;
}
__device__ __forceinline__ float wred_max(float v) {
#pragma unroll
  for (int off = 32; off; off >>= 1) v = fmaxf(v, __shfl_xor(v, off));
  return v;
}

// ---------------------------------------------------------------------------
// prep_gemm: M2T[l][i] = sum_j Wq[l][j]*Wk[i][j].  64x64 tiles, grid 16.
// ---------------------------------------------------------------------------
__global__ __launch_bounds__(256) void prep_gemm(
    const float* __restrict__ Wq, const float* __restrict__ Wk,
    float* __restrict__ M2T) {
  const int tid = threadIdx.x;
  const int l0 = (blockIdx.x >> 2) * 64, i0 = (blockIdx.x & 3) * 64;
  __shared__ float As[64][68], Bs[64][68];
  const int tl = tid >> 4, ti = tid & 15;
  float acc[4][4];
#pragma unroll
  for (int r = 0; r < 4; ++r)
#pragma unroll
    for (int c = 0; c < 4; ++c) acc[r][c] = 0.f;

  for (int kc = 0; kc < 4; ++kc) {
    const int k0 = kc * 64;
#pragma unroll
    for (int it = 0; it < 4; ++it) {
      int idx = it * 256 + tid;
      int row = idx >> 4, c4 = idx & 15;
      *(float4*)(&As[row][c4 * 4]) =
          *(const float4*)(Wq + (size_t)(l0 + row) * HH + k0 + c4 * 4);
      *(float4*)(&Bs[row][c4 * 4]) =
          *(const float4*)(Wk + (size_t)(i0 + row) * HH + k0 + c4 * 4);
    }
    __syncthreads();
#pragma unroll 4
    for (int k4 = 0; k4 < 16; ++k4) {
      float4 a4[4], b4[4];
#pragma unroll
      for (int r = 0; r < 4; ++r) a4[r] = *(const float4*)(&As[tl * 4 + r][k4 * 4]);
#pragma unroll
      for (int c = 0; c < 4; ++c) b4[c] = *(const float4*)(&Bs[ti * 4 + c][k4 * 4]);
#pragma unroll
      for (int r = 0; r < 4; ++r)
#pragma unroll
        for (int c = 0; c < 4; ++c)
          acc[r][c] += a4[r].x * b4[c].x + a4[r].y * b4[c].y +
                       a4[r].z * b4[c].z + a4[r].w * b4[c].w;
    }
    __syncthreads();
  }
#pragma unroll
  for (int r = 0; r < 4; ++r) {
    float4 o = make_float4(acc[r][0], acc[r][1], acc[r][2], acc[r][3]);
    *(float4*)(M2T + (size_t)(l0 + tl * 4 + r) * HH + i0 + ti * 4) = o;
  }
}

// ---------------------------------------------------------------------------
// bias_kernel: grid 513.  0..255: M2T row 256 = Wk@bq; 256..511: evec=Wq@bk;
// 512: f = bk.bq.
// ---------------------------------------------------------------------------
__global__ __launch_bounds__(256) void bias_kernel(
    const float* __restrict__ Wq, const float* __restrict__ bq,
    const float* __restrict__ Wk, const float* __restrict__ bk,
    float* __restrict__ M2T, float* __restrict__ evec, float* __restrict__ fsc) {
  const int id = blockIdx.x, tid = threadIdx.x;
  __shared__ float s4[4];
  const float* row;
  const float* vec;
  float* outp;
  if (id < 256)      { row = Wk + (size_t)id * HH;        vec = bq; outp = M2T + (size_t)256 * HH + id; }
  else if (id < 512) { row = Wq + (size_t)(id - 256) * HH; vec = bk; outp = evec + (id - 256); }
  else               { row = bk;                           vec = bq; outp = fsc; }
  float p = row[tid] * vec[tid];
  p = wred_sum(p);
  if ((tid & 63) == 0) s4[tid >> 6] = p;
  __syncthreads();
  if (tid == 0) *outp = s4[0] + s4[1] + s4[2] + s4[3];
}

// ---------------------------------------------------------------------------
// qkg: QK[b][i] = ( sum_l cs[b][l]*M2T[l][i] + dvec[i] ) / 16.  Grid 256.
// ---------------------------------------------------------------------------
__global__ __launch_bounds__(256, 4) void qkg_kernel(
    const float* __restrict__ CS, const float* __restrict__ M2T,
    float* __restrict__ QK) {
  const int tid = threadIdx.x, bb = blockIdx.x;
  __shared__ float s_cs[8][260];
#pragma unroll
  for (int it = 0; it < 2; ++it) {
    int idx = it * 256 + tid;
    int row = idx >> 6, c4 = idx & 63;
    *(float4*)(&s_cs[row][c4 * 4]) =
        *(const float4*)(CS + (size_t)(bb * 8 + row) * HH + c4 * 4);
  }
  if (tid < 8) s_cs[tid][256] = 1.0f;
  __syncthreads();
  const int bloc = tid >> 5, tx = tid & 31;
  float acc[8];
#pragma unroll
  for (int c = 0; c < 8; ++c) acc[c] = 0.f;
#pragma unroll 4
  for (int l = 0; l < 257; ++l) {
    float a = s_cs[bloc][l];
    const float* mr = M2T + (size_t)l * HH + tx * 8;
    float4 m0 = *(const float4*)(mr);
    float4 m1 = *(const float4*)(mr + 4);
    acc[0] += a * m0.x; acc[1] += a * m0.y; acc[2] += a * m0.z; acc[3] += a * m0.w;
    acc[4] += a * m1.x; acc[5] += a * m1.y; acc[6] += a * m1.z; acc[7] += a * m1.w;
  }
  float* op = QK + (size_t)(bb * 8 + bloc) * HH + tx * 8;
  *(float4*)(op)     = make_float4(acc[0] * 0.0625f, acc[1] * 0.0625f,
                                   acc[2] * 0.0625f, acc[3] * 0.0625f);
  *(float4*)(op + 4) = make_float4(acc[4] * 0.0625f, acc[5] * 0.0625f,
                                   acc[6] * 0.0625f, acc[7] * 0.0625f);
}

// ---------------------------------------------------------------------------
// attn: one block per b.  Scores only for t < cnt-1 (wave-uniform bound),
// 8 rows in flight per wave; softmax; top-8; writes attn row, selected,
// and (gather idx, weight) for summ.
// ---------------------------------------------------------------------------
__global__ __launch_bounds__(256) void attn_kernel(
    const float* __restrict__ CS, const float* __restrict__ X,
    const int* __restrict__ VM,
    const float* __restrict__ QK, const float* __restrict__ evec,
    const float* __restrict__ fsc,
    float* __restrict__ out, int* __restrict__ wsIdx, float* __restrict__ wsW) {
  const int tid = threadIdx.x, b = blockIdx.x;
  const int w = tid >> 6, lane = tid & 63;
  __shared__ float s_qk[HH];
  __shared__ float s_sc[TT], s_cand[TT];
  __shared__ int   s_hist[TT];
  __shared__ float s_c4[4], s_r4[4], s_m4[4];
  __shared__ int   s_selI[KK];
  __shared__ float s_selV[KK];
  __shared__ float s_dS;

  // ---- mask + per-wave count; qk row; qb partial ----
  int m = (tid < TT) ? (VM[(size_t)b * TT + tid] != 0) : 0;
  unsigned long long bal = __ballot(m);
  if (lane == 0) s_c4[w] = (float)__popcll(bal);
  s_qk[tid] = QK[(size_t)b * HH + tid];                 // pre-scaled by 1/16
  float rq = CS[(size_t)b * HH + tid] * evec[tid];
  rq = wred_sum(rq);
  if (lane == 0) s_r4[w] = rq;
  __syncthreads();

  const int cnt = (int)(s_c4[0] + s_c4[1] + s_c4[2] + s_c4[3]);
  const int hist_n = cnt - 1;            // score rows t in [0, hist_n)
  if (tid < TT) s_hist[tid] = (m && (tid < hist_n)) ? 1 : 0;
  const float qb = (s_r4[0] + s_r4[1] + s_r4[2] + s_r4[3] + fsc[0]) * 0.0625f;

  // ---- scores: wave w owns t = w, w+4, w+8, ...; 8 rows in flight ----
  {
    const float* xrow = X + (size_t)b * TT * HH + lane * 4;
    const float4 q4 = ((const float4*)s_qk)[lane];
    int t = w;
    for (; t + 28 < hist_n; t += 32) {
      float4 xv[8];
#pragma unroll
      for (int j = 0; j < 8; ++j)
        xv[j] = *(const float4*)(xrow + (size_t)(t + 4 * j) * HH);
      float pr[8];
#pragma unroll
      for (int j = 0; j < 8; ++j)
        pr[j] = xv[j].x * q4.x + xv[j].y * q4.y + xv[j].z * q4.z + xv[j].w * q4.w;
#pragma unroll
      for (int off = 32; off; off >>= 1)
#pragma unroll
        for (int j = 0; j < 8; ++j) pr[j] += __shfl_xor(pr[j], off);
      if (lane == 0) {
#pragma unroll
        for (int j = 0; j < 8; ++j) s_sc[t + 4 * j] = pr[j] + qb;
      }
    }
    for (; t < hist_n; t += 4) {
      float4 xv = *(const float4*)(xrow + (size_t)t * HH);
      float p = xv.x * q4.x + xv.y * q4.y + xv.z * q4.z + xv.w * q4.w;
      p = wred_sum(p);
      if (lane == 0) s_sc[t] = p + qb;
    }
  }
  __syncthreads();

  // ---- masked softmax: wave reduce + 4-entry combine ----
  const int hist = (tid < TT) ? s_hist[tid] : 0;
  float v = hist ? s_sc[tid] : -3.4e38f;
  float wm = wred_max(v);
  if (lane == 0) s_m4[w] = wm;
  __syncthreads();
  const float mx = fmaxf(fmaxf(s_m4[0], s_m4[1]), fmaxf(s_m4[2], s_m4[3]));
  float p = hist ? expf(v - mx) : 0.f;
  float ws_ = wred_sum(p);
  if (lane == 0) s_r4[w] = ws_;
  __syncthreads();
  const float denom = s_r4[0] + s_r4[1] + s_r4[2] + s_r4[3];
  if (tid < TT) s_cand[tid] = hist ? (p / denom) : -1.0f;
  __syncthreads();

  // ---- top-8 (wave 0): value desc, index asc -- matches lax.top_k ----
  if (tid < 64) {
    float lv[4]; int lt[4];
#pragma unroll
    for (int q = 0; q < 4; ++q) {
      int t = tid + 64 * q;
      lv[q] = (t < TT) ? s_cand[t] : -2.0f;
      lt[q] = t;
    }
    for (int r = 0; r < KK; ++r) {
      float bv = -2.5f; int bi = 1 << 30;
#pragma unroll
      for (int q = 0; q < 4; ++q)
        if (lv[q] > bv) { bv = lv[q]; bi = lt[q]; }
#pragma unroll
      for (int off = 32; off; off >>= 1) {
        float ov = __shfl_xor(bv, off);
        int   oi = __shfl_xor(bi, off);
        if (ov > bv || (ov == bv && oi < bi)) { bv = ov; bi = oi; }
      }
      if (tid == 0) { s_selI[r] = bi; s_selV[r] = bv; }
#pragma unroll
      for (int q = 0; q < 4; ++q)
        if (lt[q] == bi) lv[q] = -3.0f;
    }
    if (tid == 0) {
      float S = 0.f;
#pragma unroll
      for (int r = 0; r < KK; ++r) S += fmaxf(s_selV[r], 0.f);
      s_dS = fmaxf(S, 1.1920929e-07f);
    }
  }
  __syncthreads();

  // ---- outputs ----
  float* out_attn = out + (size_t)BB * HH + (size_t)b * TT;
  if (tid < TT) out_attn[tid] = 0.f;
  __syncthreads();
  if (tid < KK) {
    float vvv = s_selV[tid];
    int   bi  = s_selI[tid];
    float wf  = fmaxf(vvv, 0.f) / s_dS;
    int ok = (vvv >= 0.f);
    if (ok) out_attn[bi] = wf;
    out[(size_t)BB * HH + (size_t)BB * TT + (size_t)b * KK + tid] =
        ok ? (float)bi : -1.0f;
    wsIdx[b * KK + tid] = ok ? bi : 0;
    wsW[b * KK + tid] = wf;
  }
}

// ---------------------------------------------------------------------------
// summ: 256 blocks x 8 b's = 64 gathered rows/block.  8x8 register-tiled
// fp32 GEMM vs Wv, fused relu + per-b weighted reduction.
// ---------------------------------------------------------------------------
__global__ __launch_bounds__(256) void summ_kernel(
    const float* __restrict__ X, const float* __restrict__ Wv,
    const float* __restrict__ bvv,
    const int* __restrict__ wsIdx, const float* __restrict__ wsW,
    float* __restrict__ out) {
  const int tid = threadIdx.x, bb = blockIdx.x;
  __shared__ float xs[64 * XP];
  __shared__ int   s_gi[64];
  __shared__ float s_w[64];
  if (tid < 64) {
    s_gi[tid] = wsIdx[bb * 64 + tid];
    s_w[tid]  = wsW[bb * 64 + tid];
  }
  __syncthreads();
#pragma unroll
  for (int it = 0; it < 16; ++it) {
    int fidx = it * 256 + tid;
    int row = fidx >> 6, c = fidx & 63;
    int bloc = bb * 8 + (row >> 3);
    int t = s_gi[row];
    float4 xv = *(const float4*)(X + ((size_t)bloc * TT + t) * HH + c * 4);
    *(float4*)(xs + row * XP + c * 4) = xv;
  }
  __syncthreads();

  const int ty = tid >> 5, tx = tid & 31;
  float accr[8][8];
#pragma unroll
  for (int r = 0; r < 8; ++r)
#pragma unroll
    for (int c = 0; c < 8; ++c) accr[r][c] = 0.f;

  const float* wvp = Wv + tx * 8;
  for (int ig = 0; ig < 64; ++ig) {
    float4 a4[8];
#pragma unroll
    for (int r = 0; r < 8; ++r)
      a4[r] = *(const float4*)(xs + (ty * 8 + r) * XP + ig * 4);
#pragma unroll
    for (int k = 0; k < 4; ++k) {
      const float* wrow = wvp + (size_t)(ig * 4 + k) * HH;
      float4 w0 = *(const float4*)(wrow);
      float4 w1 = *(const float4*)(wrow + 4);
#pragma unroll
      for (int r = 0; r < 8; ++r) {
        float av = (k == 0) ? a4[r].x : (k == 1) ? a4[r].y
                 : (k == 2) ? a4[r].z : a4[r].w;
        accr[r][0] += av * w0.x; accr[r][1] += av * w0.y;
        accr[r][2] += av * w0.z; accr[r][3] += av * w0.w;
        accr[r][4] += av * w1.x; accr[r][5] += av * w1.y;
        accr[r][6] += av * w1.z; accr[r][7] += av * w1.w;
      }
    }
  }
  float w8[8];
#pragma unroll
  for (int r = 0; r < 8; ++r) w8[r] = s_w[ty * 8 + r];
  float4 b0 = *(const float4*)(bvv + tx * 8);
  float4 b1 = *(const float4*)(bvv + tx * 8 + 4);
  float bc[8] = {b0.x, b0.y, b0.z, b0.w, b1.x, b1.y, b1.z, b1.w};
  float ob[8];
#pragma unroll
  for (int c = 0; c < 8; ++c) {
    float s = 0.f;
#pragma unroll
    for (int r = 0; r < 8; ++r) s += w8[r] * fmaxf(accr[r][c] + bc[c], 0.f);
    ob[c] = s;
  }
  float* op = out + (size_t)(bb * 8 + ty) * HH + tx * 8;
  *(float4*)(op)     = make_float4(ob[0], ob[1], ob[2], ob[3]);
  *(float4*)(op + 4) = make_float4(ob[4], ob[5], ob[6], ob[7]);
}

// ---------------------------------------------------------------------------
extern "C" void kernel_launch(void* const* d_in, const int* in_sizes, int n_in,
                              void* d_out, int out_size, void* d_ws, size_t ws_size,
                              hipStream_t stream) {
  const float* cs  = (const float*)d_in[0];
  const float* X   = (const float*)d_in[1];
  const int*   vm  = (const int*)d_in[2];
  const float* Wq  = (const float*)d_in[3];
  const float* bq  = (const float*)d_in[4];
  const float* Wk  = (const float*)d_in[5];
  const float* bk  = (const float*)d_in[6];
  const float* Wv  = (const float*)d_in[7];
  const float* bvp = (const float*)d_in[8];
  float* out = (float*)d_out;
  float* ws  = (float*)d_ws;

  float* M2T  = ws + WS_M2T;
  float* evec = ws + WS_EVEC;
  float* fsc  = ws + WS_F;
  float* QK   = ws + WS_QK;
  int*   wsI  = (int*)(ws + WS_IDX);
  float* wsW  = ws + WS_W;

  hipLaunchKernelGGL(prep_gemm, dim3(16), dim3(256), 0, stream, Wq, Wk, M2T);
  hipLaunchKernelGGL(bias_kernel, dim3(513), dim3(256), 0, stream,
                     Wq, bq, Wk, bk, M2T, evec, fsc);
  hipLaunchKernelGGL(qkg_kernel, dim3(BB / 8), dim3(256), 0, stream,
                     cs, M2T, QK);
  hipLaunchKernelGGL(attn_kernel, dim3(BB), dim3(256), 0, stream,
                     cs, X, vm, QK, evec, fsc, out, wsI, wsW);
  hipLaunchKernelGGL(summ_kernel, dim3(BB / 8), dim3(256), 0, stream,
                     X, Wv, bvp, wsI, wsW, out);
}